// Round 11
// baseline (81.267 us; speedup 1.0000x reference)
//
#include <hip/hip_runtime.h>
#include <hip/hip_bf16.h>

namespace {

constexpr int Bsz = 64, Cch = 3, Himg = 224, Wimg = 224, Ppat = 16;
constexpr int Dm = 768, NPW = 14, NPATCH = 196, SEQn = 197;
constexpr int Mtot = Bsz * NPATCH;   // 12544
constexpr int Ktot = 768, Ntot = 768;
constexpr int BM = 64, BN = 128, BK = 64;
constexpr int MT = Mtot / BM;        // 196
constexpr int NT = Ntot / BN;        // 6
constexpr int KT = Ktot / BK;        // 12
constexpr int NBLK = MT * NT;        // 1176 (divisible by 8)
constexpr int TA = BM * BK;          // 4096 elems = 8 KB
constexpr int KSLAB = Ntot * BK;     // 49152 elems per kt-slab of Wt
constexpr size_t AP_ELEMS = (size_t)MT * KT * TA;          // 9,633,792
constexpr size_t WT_ELEMS = (size_t)KT * KSLAB;            // 589,824
constexpr size_t WS_NEED = (AP_ELEMS + WT_ELEMS) * 2;      // ~20.4 MB
constexpr int PATCH_BLK = MT * KT;                         // 2352
constexpr int WPREP_BLK = (Ktot / 8) * Ntot / 256;         // 288
constexpr int CLS_BLK = Bsz * Dm / 256;                    // 192

typedef __attribute__((ext_vector_type(8))) short bf16x8;
typedef __attribute__((ext_vector_type(4))) float f32x4;

__device__ inline unsigned short f2bf(float f) {
  __bf16 h = (__bf16)f;  // RNE; clang fuses pairs into v_cvt_pk_bf16_f32
  union { __bf16 h; unsigned short u; } c;
  c.h = h;
  return c.u;
}

union Pack8 { unsigned short s[8]; uint4 v; };

// ---------------- prepass: patchify x -> Ap, W -> Wt, cls row ---------------
// Ap tile (mt,kt) [64x64]: elem (r,k) at (mt*KT+kt)*TA + ((r*BK+k)^((r&7)<<3))
//   (pre-swizzled for LINEAR global_load_lds staging -> conflict-free
//    ds_read_b128 fragment reads; m173 pattern).
// Wt: PLAIN k-major [kt][n][64] -- consumed by per-lane global fragment loads
//   in the GEMM (no LDS for B), so no swizzle and no tiling needed.
__global__ void prep_kernel(const float* __restrict__ x, const float* __restrict__ W,
                            const float* __restrict__ pos, const float* __restrict__ cls,
                            unsigned short* __restrict__ Ap, unsigned short* __restrict__ Wt,
                            float* __restrict__ out, int nPatchBlk) {
  const int bid = blockIdx.x;
  const int t = threadIdx.x;
  if (bid < nPatchBlk) {  // ---- patchify one 64x64 A-tile (direct store)
    int mt = bid / KT, kt = bid - mt * KT;
    int r = t >> 2, ks = t & 3;           // thread = one 16-px pixel row
    int m = mt * BM + r;
    int b = m / NPATCH;
    int pidx = m - b * NPATCH;
    int ph = pidx / NPW, pw = pidx - ph * NPW;
    int kg = kt * BK + ks * 16;           // multiple of 16 -> pj = 0
    int c = kg >> 8, pi = (kg >> 4) & 15;
    const float* src = x + ((size_t)(b * Cch + c) * Himg + ph * Ppat + pi) * Wimg
                       + pw * Ppat;
    float4 v0 = *reinterpret_cast<const float4*>(src + 0);
    float4 v1 = *reinterpret_cast<const float4*>(src + 4);
    float4 v2 = *reinterpret_cast<const float4*>(src + 8);
    float4 v3 = *reinterpret_cast<const float4*>(src + 12);
    Pack8 p0, p1;
    p0.s[0] = f2bf(v0.x); p0.s[1] = f2bf(v0.y); p0.s[2] = f2bf(v0.z); p0.s[3] = f2bf(v0.w);
    p0.s[4] = f2bf(v1.x); p0.s[5] = f2bf(v1.y); p0.s[6] = f2bf(v1.z); p0.s[7] = f2bf(v1.w);
    p1.s[0] = f2bf(v2.x); p1.s[1] = f2bf(v2.y); p1.s[2] = f2bf(v2.z); p1.s[3] = f2bf(v2.w);
    p1.s[4] = f2bf(v3.x); p1.s[5] = f2bf(v3.y); p1.s[6] = f2bf(v3.z); p1.s[7] = f2bf(v3.w);
    unsigned short* dst = Ap + (size_t)bid * TA;
    int g = r * BK + ks * 16;
    int sw = (r & 7) << 3;
    *reinterpret_cast<uint4*>(dst + (g ^ sw)) = p0.v;
    *reinterpret_cast<uint4*>(dst + ((g + 8) ^ sw)) = p1.v;
  } else if (bid < nPatchBlk + WPREP_BLK) {  // ---- W prep (plain k-major)
    int cid = (bid - nPatchBlk) * 256 + t;
    int kc = cid / Ntot;                      // k-chunk of 8 (0..95)
    int n = cid - kc * Ntot;                  // lanes: consecutive n -> coalesced reads
    int kt = kc >> 3;
    int kk = kc & 7;
    Pack8 p;
#pragma unroll
    for (int j = 0; j < 8; ++j) p.s[j] = f2bf(W[(size_t)(kc * 8 + j) * Ntot + n]);
    *reinterpret_cast<uint4*>(Wt + (size_t)kt * KSLAB + (size_t)n * BK + kk * 8) = p.v;
  } else {  // ---- class-token row (s = 0)
    int i = (bid - nPatchBlk - WPREP_BLK) * 256 + t;
    int b = i / Dm;
    int d = i - b * Dm;
    out[(size_t)b * (SEQn * Dm) + d] = cls[d] + pos[d];
  }
}

// ---------------- GEMM: A via LDS (8 KB, single buffer), B via registers ----
// Cuts LDS-unit time per block-step 770->~260 cy (16 ds_read_b128 + 8 KB DMA
// vs 48 reads + 24 KB). B frags are 8 global_load_dwordx4/lane/kt with
// immediate offsets from the L2-resident 1.2 MB Wt. Barrier rhythm kept (the
// R7 lesson: naked fragment loads serialize; the A-barrier forces batching).
__global__ __launch_bounds__(256, 5)
void gemm_kernel(const unsigned short* __restrict__ Ap, const unsigned short* __restrict__ Wt,
                 const float* __restrict__ bias, const float* __restrict__ pos,
                 float* __restrict__ out) {
  __shared__ unsigned short A[TA];     // 8 KB

  // XCD-chunked bijective swizzle (NBLK % 8 == 0); bn fastest within a chunk
  // -> A-panel + Wt slab reused within one XCD's L2.
  const int orig = blockIdx.x;
  const int wg = (orig & 7) * (NBLK / 8) + (orig >> 3);
  const int bm = wg / NT;
  const int bn = wg - bm * NT;

  const int t = threadIdx.x;
  const int lane = t & 63;
  const int wid = t >> 6;              // 4 waves: 2 (M) x 2 (N), each 32x64
  const int wr = wid >> 1, wc = wid & 1;
  const int fr = lane & 15, fq = lane >> 4;

  const unsigned short* aSrc = Ap + (size_t)(bm * KT) * TA + t * 8;
  const unsigned short* bBase = Wt + (size_t)(bn * BN + wc * 64 + fr) * BK + fq * 8;

  auto STAGE_A = [&](int kt) {  // 2 x 16B per thread, linear dest
#pragma unroll
    for (int i = 0; i < 2; ++i)
      __builtin_amdgcn_global_load_lds(
          (const __attribute__((address_space(1))) unsigned int*)(aSrc + kt * TA + i * 2048),
          (__attribute__((address_space(3))) unsigned int*)(&A[t * 8 + i * 2048]),
          16, 0, 0);
  };

  f32x4 acc[2][4];
#pragma unroll
  for (int mi = 0; mi < 2; ++mi)
#pragma unroll
    for (int ni = 0; ni < 4; ++ni) acc[mi][ni] = {0.f, 0.f, 0.f, 0.f};

  STAGE_A(0);
#pragma unroll
  for (int kt = 0; kt < KT; ++kt) {
    // B fragments for this kt: 8 global b128 loads, immediate offsets
    const unsigned short* bP = bBase + (size_t)kt * KSLAB;
    bf16x8 breg[2][4];
#pragma unroll
    for (int ks = 0; ks < 2; ++ks)
#pragma unroll
      for (int ni = 0; ni < 4; ++ni)
        breg[ks][ni] = *reinterpret_cast<const bf16x8*>(bP + ni * 16 * BK + ks * 32);
    __syncthreads();                   // drains vmcnt(0): A in LDS, breg ready
#pragma unroll
    for (int ks = 0; ks < 2; ++ks) {
      bf16x8 af[2];
#pragma unroll
      for (int mi = 0; mi < 2; ++mi) {
        int row = wr * 32 + mi * 16 + fr;
        int idx = (row * BK + ks * 32 + fq * 8) ^ ((row & 7) << 3);
        af[mi] = *reinterpret_cast<const bf16x8*>(&A[idx]);
      }
#pragma unroll
      for (int mi = 0; mi < 2; ++mi)
#pragma unroll
        for (int ni = 0; ni < 4; ++ni)
          acc[mi][ni] = __builtin_amdgcn_mfma_f32_16x16x32_bf16(
              af[mi], breg[ks][ni], acc[mi][ni], 0, 0, 0);
    }
    if (kt + 1 < KT) {
      __syncthreads();                 // all A reads done before overwrite
      STAGE_A(kt + 1);
    }
  }

  // ---- epilogue: R5/R10 pattern (measured WRITE_SIZE == ideal 37.6 MB):
  // per (mi,j) the 4 ni-stores are adjacent, covering 256B contiguous per row.
  const int n0 = bn * BN + wc * 64;
  float bv[4];
#pragma unroll
  for (int ni = 0; ni < 4; ++ni) bv[ni] = bias[n0 + ni * 16 + fr];
#pragma unroll
  for (int mi = 0; mi < 2; ++mi) {
#pragma unroll
    for (int j = 0; j < 4; ++j) {
      int m = bm * BM + wr * 32 + mi * 16 + fq * 4 + j;
      int b = m / NPATCH;
      int s = m - b * NPATCH + 1;  // +1: class token at s=0
      float* orow = out + ((size_t)b * SEQn + s) * Dm + n0;
      const float* prow = pos + (size_t)s * Dm + n0;
#pragma unroll
      for (int ni = 0; ni < 4; ++ni) {
        int d = ni * 16 + fr;
        orow[d] = acc[mi][ni][j] + bv[ni] + prow[d];
      }
    }
  }
}

// ---------------- fallback (ws too small for Ap): A from x, B-direct --------
__global__ __launch_bounds__(256, 2)
void gemm_fb(const float* __restrict__ x, const unsigned short* __restrict__ Wt,
             const float* __restrict__ bias, const float* __restrict__ pos,
             float* __restrict__ out) {
  __shared__ unsigned short As[2][TA];

  const int orig = blockIdx.x;
  const int wg = (orig & 7) * (NBLK / 8) + (orig >> 3);
  const int bm = wg / NT;
  const int bn = wg - bm * NT;

  const int t = threadIdx.x;
  const int lane = t & 63;
  const int wid = t >> 6;
  const int wr = wid >> 1, wc = wid & 1;
  const int fr = lane & 15, fq = lane >> 4;

  const int c4 = t & 15;
  const int r0 = t >> 4;
  int a_base[4];
#pragma unroll
  for (int i = 0; i < 4; ++i) {
    int m = bm * BM + r0 + 16 * i;
    int b = m / NPATCH;
    int pidx = m - b * NPATCH;
    int ph = pidx / NPW;
    int pw = pidx - ph * NPW;
    a_base[i] = ((b * Cch) * Himg + ph * Ppat) * Wimg + pw * Ppat;
  }

  float4 av[4];
  auto LOADA = [&](int kt) {
    int kg = kt * BK + c4 * 4;
    int c = kg >> 8, pi = (kg >> 4) & 15, pj = kg & 15;
    int off = (c * Himg + pi) * Wimg + pj;
#pragma unroll
    for (int i = 0; i < 4; ++i)
      av[i] = *reinterpret_cast<const float4*>(x + a_base[i] + off);
  };
  auto WRITEA = [&](int buf) {
#pragma unroll
    for (int i = 0; i < 4; ++i) {
      int row = r0 + 16 * i;
      int idx = (row * BK + c4 * 4) ^ ((row & 7) << 3);
      ushort4 pk = make_ushort4(f2bf(av[i].x), f2bf(av[i].y), f2bf(av[i].z), f2bf(av[i].w));
      *reinterpret_cast<ushort4*>(&As[buf][idx]) = pk;
    }
  };

  const unsigned short* bBase = Wt + (size_t)(bn * BN + wc * 64 + fr) * BK + fq * 8;

  f32x4 acc[2][4];
#pragma unroll
  for (int mi = 0; mi < 2; ++mi)
#pragma unroll
    for (int ni = 0; ni < 4; ++ni) acc[mi][ni] = {0.f, 0.f, 0.f, 0.f};

  LOADA(0);
  WRITEA(0);
  __syncthreads();

  for (int kt = 0; kt < KT; ++kt) {
    const int cur = kt & 1, nxt = cur ^ 1;
    if (kt + 1 < KT) LOADA(kt + 1);
    const unsigned short* bP = bBase + (size_t)kt * KSLAB;
    bf16x8 breg[2][4];
#pragma unroll
    for (int ks = 0; ks < 2; ++ks)
#pragma unroll
      for (int ni = 0; ni < 4; ++ni)
        breg[ks][ni] = *reinterpret_cast<const bf16x8*>(bP + ni * 16 * BK + ks * 32);
#pragma unroll
    for (int ks = 0; ks < 2; ++ks) {
      bf16x8 af[2];
#pragma unroll
      for (int mi = 0; mi < 2; ++mi) {
        int row = wr * 32 + mi * 16 + fr;
        int idx = (row * BK + ks * 32 + fq * 8) ^ ((row & 7) << 3);
        af[mi] = *reinterpret_cast<const bf16x8*>(&As[cur][idx]);
      }
#pragma unroll
      for (int mi = 0; mi < 2; ++mi)
#pragma unroll
        for (int ni = 0; ni < 4; ++ni)
          acc[mi][ni] = __builtin_amdgcn_mfma_f32_16x16x32_bf16(
              af[mi], breg[ks][ni], acc[mi][ni], 0, 0, 0);
    }
    if (kt + 1 < KT) WRITEA(nxt);
    __syncthreads();
  }

  const int n0 = bn * BN + wc * 64;
  float bv[4];
#pragma unroll
  for (int ni = 0; ni < 4; ++ni) bv[ni] = bias[n0 + ni * 16 + fr];
#pragma unroll
  for (int mi = 0; mi < 2; ++mi) {
#pragma unroll
    for (int j = 0; j < 4; ++j) {
      int m = bm * BM + wr * 32 + mi * 16 + fq * 4 + j;
      int b = m / NPATCH;
      int s = m - b * NPATCH + 1;
      float* orow = out + ((size_t)b * SEQn + s) * Dm + n0;
      const float* prow = pos + (size_t)s * Dm + n0;
#pragma unroll
      for (int ni = 0; ni < 4; ++ni) {
        int d = ni * 16 + fr;
        orow[d] = acc[mi][ni][j] + bv[ni] + prow[d];
      }
    }
  }
}

}  // namespace

extern "C" void kernel_launch(void* const* d_in, const int* in_sizes, int n_in,
                              void* d_out, int out_size, void* d_ws, size_t ws_size,
                              hipStream_t stream) {
  const float* x = (const float*)d_in[0];
  const float* W = (const float*)d_in[1];
  const float* bias = (const float*)d_in[2];
  const float* pos = (const float*)d_in[3];
  const float* cls = (const float*)d_in[4];
  float* out = (float*)d_out;

  const bool pure = ws_size >= WS_NEED;
  unsigned short* Ap = (unsigned short*)d_ws;
  unsigned short* Wt = pure ? Ap + AP_ELEMS : Ap;  // fallback: Wt at ws base
  const int nPatchBlk = pure ? PATCH_BLK : 0;

  prep_kernel<<<nPatchBlk + WPREP_BLK + CLS_BLK, 256, 0, stream>>>(
      x, W, pos, cls, Ap, Wt, out, nPatchBlk);
  if (pure)
    gemm_kernel<<<NBLK, 256, 0, stream>>>(Ap, Wt, bias, pos, out);
  else
    gemm_fb<<<NBLK, 256, 0, stream>>>(x, Wt, bias, pos, out);
}

// Round 12
// 39.717 us; speedup vs baseline: 2.0462x; 2.0462x over previous
//
#include <hip/hip_runtime.h>
#include <hip/hip_bf16.h>

namespace {

constexpr int Bsz = 64, Cch = 3, Himg = 224, Wimg = 224, Ppat = 16;
constexpr int Dm = 768, NPW = 14, NPATCH = 196, SEQn = 197;
constexpr int Mtot = Bsz * NPATCH;   // 12544
constexpr int Ktot = 768, Ntot = 768;
constexpr int BM = 64, BN = 128, BK = 64;
constexpr int MT = Mtot / BM;        // 196
constexpr int NT = Ntot / BN;        // 6
constexpr int KT = Ktot / BK;        // 12
constexpr int NBLK = MT * NT;        // 1176 (divisible by 8)
constexpr int TA = BM * BK;          // 4096 elems = 8 KB
constexpr int TB = BN * BK;          // 8192 elems = 16 KB
constexpr size_t AP_ELEMS = (size_t)MT * KT * TA;          // 9,633,792
constexpr size_t WT_ELEMS = (size_t)NT * KT * TB;          // 589,824
constexpr size_t WS_NEED = (AP_ELEMS + WT_ELEMS) * 2;      // ~20.4 MB
constexpr int PATCH_BLK = MT * KT;                         // 2352
constexpr int WPREP_BLK = (Ktot / 8) * Ntot / 256;         // 288
constexpr int CLS_BLK = Bsz * Dm / 256;                    // 192

typedef __attribute__((ext_vector_type(8))) short bf16x8;
typedef __attribute__((ext_vector_type(4))) float f32x4;

__device__ inline unsigned short f2bf(float f) {
  __bf16 h = (__bf16)f;  // RNE; clang fuses pairs into v_cvt_pk_bf16_f32
  union { __bf16 h; unsigned short u; } c;
  c.h = h;
  return c.u;
}

union Pack8 { unsigned short s[8]; uint4 v; };

// ---------------- prepass: patchify x -> Ap, W -> Wt, cls row ---------------
// Ap tile (mt,kt) [64x64]: elem (r,k) at (mt*KT+kt)*TA + ((r*BK+k)^((r&7)<<3))
// Wt tile (nb,kt) [128x64]: elem (n',k') at (nb*KT+kt)*TB + ((n'*BK+k')^((n'&7)<<3))
// Pre-swizzled so LINEAR global_load_lds staging yields the swizzled LDS
// image the ds_read_b128 fragment reads expect (m173 pattern). XOR acts on
// 16B granules, so granule-aligned uint4 writes stay contiguous.
__global__ void prep_kernel(const float* __restrict__ x, const float* __restrict__ W,
                            const float* __restrict__ pos, const float* __restrict__ cls,
                            unsigned short* __restrict__ Ap, unsigned short* __restrict__ Wt,
                            float* __restrict__ out, int nPatchBlk) {
  const int bid = blockIdx.x;
  const int t = threadIdx.x;
  if (bid < nPatchBlk) {  // ---- patchify one 64x64 A-tile (direct store)
    int mt = bid / KT, kt = bid - mt * KT;
    int r = t >> 2, ks = t & 3;           // thread = one 16-px pixel row
    int m = mt * BM + r;
    int b = m / NPATCH;
    int pidx = m - b * NPATCH;
    int ph = pidx / NPW, pw = pidx - ph * NPW;
    int kg = kt * BK + ks * 16;           // multiple of 16 -> pj = 0
    int c = kg >> 8, pi = (kg >> 4) & 15;
    const float* src = x + ((size_t)(b * Cch + c) * Himg + ph * Ppat + pi) * Wimg
                       + pw * Ppat;
    float4 v0 = *reinterpret_cast<const float4*>(src + 0);
    float4 v1 = *reinterpret_cast<const float4*>(src + 4);
    float4 v2 = *reinterpret_cast<const float4*>(src + 8);
    float4 v3 = *reinterpret_cast<const float4*>(src + 12);
    Pack8 p0, p1;
    p0.s[0] = f2bf(v0.x); p0.s[1] = f2bf(v0.y); p0.s[2] = f2bf(v0.z); p0.s[3] = f2bf(v0.w);
    p0.s[4] = f2bf(v1.x); p0.s[5] = f2bf(v1.y); p0.s[6] = f2bf(v1.z); p0.s[7] = f2bf(v1.w);
    p1.s[0] = f2bf(v2.x); p1.s[1] = f2bf(v2.y); p1.s[2] = f2bf(v2.z); p1.s[3] = f2bf(v2.w);
    p1.s[4] = f2bf(v3.x); p1.s[5] = f2bf(v3.y); p1.s[6] = f2bf(v3.z); p1.s[7] = f2bf(v3.w);
    unsigned short* dst = Ap + (size_t)bid * TA;
    int g = r * BK + ks * 16;
    int sw = (r & 7) << 3;
    *reinterpret_cast<uint4*>(dst + (g ^ sw)) = p0.v;
    *reinterpret_cast<uint4*>(dst + ((g + 8) ^ sw)) = p1.v;
  } else if (bid < nPatchBlk + WPREP_BLK) {  // ---- W prep (swizzled tiles)
    int cid = (bid - nPatchBlk) * 256 + t;
    int kc = cid / Ntot;                      // k-chunk of 8 (0..95)
    int n = cid - kc * Ntot;
    int nb = n >> 7;                          // 0..5
    int np = n & 127;
    int kt = kc >> 3;
    int k8 = (kc & 7) * 8;
    Pack8 p;
#pragma unroll
    for (int j = 0; j < 8; ++j) p.s[j] = f2bf(W[(size_t)(kc * 8 + j) * Ntot + n]);
    int sidx = (np * BK + k8) ^ ((np & 7) << 3);
    *reinterpret_cast<uint4*>(Wt + (size_t)(nb * KT + kt) * TB + sidx) = p.v;
  } else {  // ---- class-token row (s = 0)
    int i = (bid - nPatchBlk - WPREP_BLK) * 256 + t;
    int b = i / Dm;
    int d = i - b * Dm;
    out[(size_t)b * (SEQn * Dm) + d] = cls[d] + pos[d];
  }
}

// ---------------- GEMM: 64x128 block, 2 waves x (64x64), SINGLE buffer ------
// Wave-tile intensity: 64x64 wave halves LDS bytes per FLOP vs 32x64 (R10):
// per block-step 32 wave ds_read_b128 + 24 KB DMA (~576 cy) for 1M FLOP vs
// R10's 48+DMA (~770 cy). 24 KB LDS, 128 thr -> 6 blocks/CU, grid 1176 all
// co-resident; same proven single-buffer barrier rhythm (compiler-scheduled).
__global__ __launch_bounds__(128, 3)
void gemm_kernel(const unsigned short* __restrict__ Ap, const unsigned short* __restrict__ Wt,
                 const float* __restrict__ bias, const float* __restrict__ pos,
                 float* __restrict__ out) {
  __shared__ unsigned short A[TA];     // 8 KB
  __shared__ unsigned short B[TB];     // 16 KB

  // XCD-chunked bijective swizzle (NBLK % 8 == 0); bn fastest within a chunk
  // -> A-panel reused across the 6 bn's within one XCD's L2.
  const int orig = blockIdx.x;
  const int wg = (orig & 7) * (NBLK / 8) + (orig >> 3);
  const int bm = wg / NT;
  const int bn = wg - bm * NT;

  const int t = threadIdx.x;
  const int lane = t & 63;
  const int wc = t >> 6;               // 2 waves: 1 (M) x 2 (N), each 64x64
  const int fr = lane & 15, fq = lane >> 4;

  const unsigned short* aSrc = Ap + (size_t)(bm * KT) * TA + t * 8;
  const unsigned short* bSrc = Wt + (size_t)(bn * KT) * TB + t * 8;

  auto STAGE = [&](int kt) {  // 12 x 16B per thread, linear dest
#pragma unroll
    for (int i = 0; i < 4; ++i)
      __builtin_amdgcn_global_load_lds(
          (const __attribute__((address_space(1))) unsigned int*)(aSrc + kt * TA + i * 1024),
          (__attribute__((address_space(3))) unsigned int*)(&A[t * 8 + i * 1024]),
          16, 0, 0);
#pragma unroll
    for (int i = 0; i < 8; ++i)
      __builtin_amdgcn_global_load_lds(
          (const __attribute__((address_space(1))) unsigned int*)(bSrc + kt * TB + i * 1024),
          (__attribute__((address_space(3))) unsigned int*)(&B[t * 8 + i * 1024]),
          16, 0, 0);
  };

  f32x4 acc[4][4];
#pragma unroll
  for (int mi = 0; mi < 4; ++mi)
#pragma unroll
    for (int ni = 0; ni < 4; ++ni) acc[mi][ni] = {0.f, 0.f, 0.f, 0.f};

  for (int kt = 0; kt < KT; ++kt) {
    STAGE(kt);
    __syncthreads();                   // drains vmcnt(0): tile resident
#pragma unroll
    for (int ks = 0; ks < 2; ++ks) {
      bf16x8 af[4], bfr[4];
#pragma unroll
      for (int mi = 0; mi < 4; ++mi) {
        int row = mi * 16 + fr;
        int idx = (row * BK + ks * 32 + fq * 8) ^ ((row & 7) << 3);
        af[mi] = *reinterpret_cast<const bf16x8*>(&A[idx]);
      }
#pragma unroll
      for (int ni = 0; ni < 4; ++ni) {
        int n = wc * 64 + ni * 16 + fr;
        int idx = (n * BK + ks * 32 + fq * 8) ^ ((n & 7) << 3);
        bfr[ni] = *reinterpret_cast<const bf16x8*>(&B[idx]);
      }
#pragma unroll
      for (int mi = 0; mi < 4; ++mi)
#pragma unroll
        for (int ni = 0; ni < 4; ++ni)
          acc[mi][ni] = __builtin_amdgcn_mfma_f32_16x16x32_bf16(
              af[mi], bfr[ni], acc[mi][ni], 0, 0, 0);
    }
    if (kt + 1 < KT) __syncthreads();  // all reads done before next overwrite
  }

  // ---- epilogue: R5/R10 pattern (measured WRITE_SIZE == ideal 37.6 MB):
  // per (mi,j) the 4 ni-stores are adjacent, covering 256B contiguous per row.
  const int n0 = bn * BN + wc * 64;
  float bv[4];
#pragma unroll
  for (int ni = 0; ni < 4; ++ni) bv[ni] = bias[n0 + ni * 16 + fr];
#pragma unroll
  for (int mi = 0; mi < 4; ++mi) {
#pragma unroll
    for (int j = 0; j < 4; ++j) {
      int m = bm * BM + mi * 16 + fq * 4 + j;
      int b = m / NPATCH;
      int s = m - b * NPATCH + 1;  // +1: class token at s=0
      float* orow = out + ((size_t)b * SEQn + s) * Dm + n0;
      const float* prow = pos + (size_t)s * Dm + n0;
#pragma unroll
      for (int ni = 0; ni < 4; ++ni) {
        int d = ni * 16 + fr;
        orow[d] = acc[mi][ni][j] + bv[ni] + prow[d];
      }
    }
  }
}

// ---------------- fallback (ws too small): stages A in-kernel (R10's) -------
__global__ __launch_bounds__(512, 6)
void gemm_fb(const float* __restrict__ x, const unsigned short* __restrict__ Wt,
             const float* __restrict__ bias, const float* __restrict__ pos,
             float* __restrict__ out) {
  __shared__ unsigned short As[2][TA];
  __shared__ unsigned short Bs[2][TB];

  const int orig = blockIdx.x;
  const int wg = (orig & 7) * (NBLK / 8) + (orig >> 3);
  const int bm = wg / NT;
  const int bn = wg - bm * NT;

  const int t = threadIdx.x;
  const int lane = t & 63;
  const int wid = t >> 6;              // 8 waves: 2 (M) x 4 (N)
  const int wr = wid >> 2, wc = wid & 3;
  const int fr = lane & 15, fq = lane >> 4;

  const int c4 = t & 15;
  const int r0 = t >> 4;
  int a_base[2];
#pragma unroll
  for (int i = 0; i < 2; ++i) {
    int m = bm * BM + r0 + 32 * i;
    int b = m / NPATCH;
    int pidx = m - b * NPATCH;
    int ph = pidx / NPW;
    int pw = pidx - ph * NPW;
    a_base[i] = ((b * Cch) * Himg + ph * Ppat) * Wimg + pw * Ppat;
  }
  const unsigned short* wt_base = Wt + (size_t)bn * (KT * TB);

  float4 av[2];
  auto LOADA = [&](int kt) {
    int kg = kt * BK + c4 * 4;
    int c = kg >> 8, pi = (kg >> 4) & 15, pj = kg & 15;
    int off = (c * Himg + pi) * Wimg + pj;
#pragma unroll
    for (int i = 0; i < 2; ++i)
      av[i] = *reinterpret_cast<const float4*>(x + a_base[i] + off);
  };
  auto WRITEA = [&](int buf) {
#pragma unroll
    for (int i = 0; i < 2; ++i) {
      int row = r0 + 32 * i;
      int idx = (row * BK + c4 * 4) ^ ((row & 7) << 3);
      ushort4 pk = make_ushort4(f2bf(av[i].x), f2bf(av[i].y), f2bf(av[i].z), f2bf(av[i].w));
      *reinterpret_cast<ushort4*>(&As[buf][idx]) = pk;
    }
  };
  auto STAGEB = [&](int buf, int kt) {
    const unsigned short* src = wt_base + kt * TB + t * 8;
#pragma unroll
    for (int i = 0; i < 2; ++i) {
      __builtin_amdgcn_global_load_lds(
          (const __attribute__((address_space(1))) unsigned int*)(src + i * 4096),
          (__attribute__((address_space(3))) unsigned int*)(&Bs[buf][t * 8 + i * 4096]),
          16, 0, 0);
    }
  };

  f32x4 acc[2][2];
#pragma unroll
  for (int mi = 0; mi < 2; ++mi)
#pragma unroll
    for (int ni = 0; ni < 2; ++ni) acc[mi][ni] = {0.f, 0.f, 0.f, 0.f};

  LOADA(0);
  STAGEB(0, 0);
  WRITEA(0);
  __syncthreads();

  for (int kt = 0; kt < KT; ++kt) {
    const int cur = kt & 1, nxt = cur ^ 1;
    if (kt + 1 < KT) {
      LOADA(kt + 1);
      STAGEB(nxt, kt + 1);
    }
#pragma unroll
    for (int ks = 0; ks < 2; ++ks) {
      bf16x8 af[2], bfr[2];
#pragma unroll
      for (int mi = 0; mi < 2; ++mi) {
        int row = wr * 32 + mi * 16 + fr;
        int idx = (row * BK + ks * 32 + fq * 8) ^ ((row & 7) << 3);
        af[mi] = *reinterpret_cast<const bf16x8*>(&As[cur][idx]);
      }
#pragma unroll
      for (int ni = 0; ni < 2; ++ni) {
        int n = wc * 32 + ni * 16 + fr;
        int idx = (n * BK + ks * 32 + fq * 8) ^ ((n & 7) << 3);
        bfr[ni] = *reinterpret_cast<const bf16x8*>(&Bs[cur][idx]);
      }
#pragma unroll
      for (int mi = 0; mi < 2; ++mi)
#pragma unroll
        for (int ni = 0; ni < 2; ++ni)
          acc[mi][ni] = __builtin_amdgcn_mfma_f32_16x16x32_bf16(
              af[mi], bfr[ni], acc[mi][ni], 0, 0, 0);
    }
    if (kt + 1 < KT) WRITEA(nxt);
    __syncthreads();
  }

  const int n0 = bn * BN + wc * 32;
  float bv[2];
#pragma unroll
  for (int ni = 0; ni < 2; ++ni) bv[ni] = bias[n0 + ni * 16 + fr];
#pragma unroll
  for (int mi = 0; mi < 2; ++mi) {
#pragma unroll
    for (int j = 0; j < 4; ++j) {
      int m = bm * BM + wr * 32 + mi * 16 + fq * 4 + j;
      int b = m / NPATCH;
      int s = m - b * NPATCH + 1;
      float* orow = out + ((size_t)b * SEQn + s) * Dm + n0;
      const float* prow = pos + (size_t)s * Dm + n0;
#pragma unroll
      for (int ni = 0; ni < 2; ++ni) {
        int d = ni * 16 + fr;
        orow[d] = acc[mi][ni][j] + bv[ni] + prow[d];
      }
    }
  }
}

}  // namespace

extern "C" void kernel_launch(void* const* d_in, const int* in_sizes, int n_in,
                              void* d_out, int out_size, void* d_ws, size_t ws_size,
                              hipStream_t stream) {
  const float* x = (const float*)d_in[0];
  const float* W = (const float*)d_in[1];
  const float* bias = (const float*)d_in[2];
  const float* pos = (const float*)d_in[3];
  const float* cls = (const float*)d_in[4];
  float* out = (float*)d_out;

  const bool pure = ws_size >= WS_NEED;
  unsigned short* Ap = (unsigned short*)d_ws;
  unsigned short* Wt = pure ? Ap + AP_ELEMS : Ap;  // fallback: Wt at ws base
  const int nPatchBlk = pure ? PATCH_BLK : 0;

  prep_kernel<<<nPatchBlk + WPREP_BLK + CLS_BLK, 256, 0, stream>>>(
      x, W, pos, cls, Ap, Wt, out, nPatchBlk);
  if (pure)
    gemm_kernel<<<NBLK, 128, 0, stream>>>(Ap, Wt, bias, pos, out);
  else
    gemm_fb<<<NBLK, 512, 0, stream>>>(x, Wt, bias, pos, out);
}